// Round 4
// baseline (286.059 us; speedup 1.0000x reference)
//
#include <hip/hip_runtime.h>

// FFF tree-routing MLP, MI355X — fp32 I/O. Round 9: pin-the-operands probe.
//
// R8 post-mortem: asm-batched w loads compiled+passed but dur unchanged
// (~114us fused) and VGPR=48 -> compiler satisfied the 8 asm "=v" f4 by
// spilling xf[] to scratch; per-level chain still ~6K cycles. Two live
// theories: (T-chain) operand serialization (now via scratch reloads);
// (T-BW) 805MB of w_in rows through L3/fabric ~ a 10 TB/s wall. R9 decides:
// x0..x7 are pinned in VGPRs with empty-asm "+v" every level (allocator
// cannot spill across the pin), launch_bounds(256,4). Litmus: VGPR>=84.
// T-chain -> phaseA 35-55us; T-BW -> ~80us unchanged, next round cuts bytes.
// Fusion dropped (measured gain zero: two BW consumers don't overlap).
// phaseB5: register-resident 16 rows (asm loads + pins), 1024 blocks,
// 544B LDS (4 blocks/CU vs phaseB4's 2 at 65KB); scatter pre-expands g into
// 16 slots so phaseB staging is 4 coalesced f4 loads/token. All FP orders
// and the slot mapping are bit-identical to the R8-passing kernel.

#define D_IN    2048
#define D_OUT   2048
#define DEPTHP1 12
#define N_NODES 4095
#define N_TOK   8192
#define N_LEAF  2048

typedef float f4 __attribute__((ext_vector_type(4)));

// ---------------- K1: transpose w_out + zero hist/cnt ----------------------
__global__ __launch_bounds__(256) void transpose_wout64z(
    const float* __restrict__ in, float* __restrict__ out,
    int* __restrict__ hc /* hist+cnt, 2*N_LEAF contiguous */) {
    __shared__ float tile[64][65];
    const int fb = blockIdx.y * 64 + blockIdx.x;     // 0..2047
    const int tx = threadIdx.x;                      // 0..63
    const int ty = threadIdx.y;                      // 0..3
    if (fb < 16) {
        const int i = fb * 256 + ty * 64 + tx;       // 0..4095
        hc[i] = 0;
    }
    const int n0 = blockIdx.x * 64;
    const int j0 = blockIdx.y * 64;
    const int n = n0 + tx;
#pragma unroll
    for (int k = 0; k < 16; k++) {
        const int r = ty * 16 + k;
        if (n < N_NODES) tile[r][tx] = in[(size_t)(j0 + r) * N_NODES + n];
    }
    __syncthreads();
#pragma unroll
    for (int k = 0; k < 16; k++) {
        const int r = ty * 16 + k;
        const int nn = n0 + r;
        if (nn < N_NODES) out[(size_t)nn * D_OUT + (j0 + tx)] = tile[tx][r];
    }
}

// ---------------- K2: phase A — tree descent, operands pinned in VGPRs -----
__global__ __launch_bounds__(256, 4) void phaseA4(
    const float* __restrict__ x,      // [N_TOK, D_IN]
    const float* __restrict__ w_in,   // [N_NODES, D_IN]
    float* __restrict__ s_all,        // [N_TOK, 12] RAW scores
    int* __restrict__ leaf,           // [N_TOK]
    int* __restrict__ hist) {         // [N_LEAF]
    const int wave  = threadIdx.x >> 6;
    const int lane  = threadIdx.x & 63;
    const int token = blockIdx.x * 4 + wave;

    const f4* xrow = (const f4*)(x + (size_t)token * D_IN);
    f4 x0 = xrow[lane +   0], x1 = xrow[lane +  64];
    f4 x2 = xrow[lane + 128], x3 = xrow[lane + 192];
    f4 x4 = xrow[lane + 256], x5 = xrow[lane + 320];
    f4 x6 = xrow[lane + 384], x7 = xrow[lane + 448];

    const unsigned voffA = (unsigned)lane * 16u;     // bytes
    const unsigned voffB = voffA + 4096u;            // c=4..7 window

    int cur = 0;
    float sc[DEPTHP1];
#pragma unroll
    for (int l = 0; l < DEPTHP1; l++) {
        const float* wbase = w_in + (size_t)cur * D_IN;   // wave-uniform (SGPR)
        f4 w0, w1, w2, w3, w4, w5, w6, w7;
        asm volatile("global_load_dwordx4 %0, %1, %2"             : "=v"(w0) : "v"(voffA), "s"(wbase));
        asm volatile("global_load_dwordx4 %0, %1, %2 offset:1024" : "=v"(w1) : "v"(voffA), "s"(wbase));
        asm volatile("global_load_dwordx4 %0, %1, %2 offset:2048" : "=v"(w2) : "v"(voffA), "s"(wbase));
        asm volatile("global_load_dwordx4 %0, %1, %2 offset:3072" : "=v"(w3) : "v"(voffA), "s"(wbase));
        asm volatile("global_load_dwordx4 %0, %1, %2"             : "=v"(w4) : "v"(voffB), "s"(wbase));
        asm volatile("global_load_dwordx4 %0, %1, %2 offset:1024" : "=v"(w5) : "v"(voffB), "s"(wbase));
        asm volatile("global_load_dwordx4 %0, %1, %2 offset:2048" : "=v"(w6) : "v"(voffB), "s"(wbase));
        asm volatile("global_load_dwordx4 %0, %1, %2 offset:3072" : "=v"(w7) : "v"(voffB), "s"(wbase));
        asm volatile("s_waitcnt vmcnt(0)"
                     : "+v"(w0), "+v"(w1), "+v"(w2), "+v"(w3),
                       "+v"(w4), "+v"(w5), "+v"(w6), "+v"(w7)
                     :: "memory");

        float p0 = 0.f, p1 = 0.f, p2 = 0.f, p3 = 0.f;
        p0 += w0[0]*x0[0] + w0[1]*x0[1] + w0[2]*x0[2] + w0[3]*x0[3];
        p0 += w1[0]*x1[0] + w1[1]*x1[1] + w1[2]*x1[2] + w1[3]*x1[3];
        p1 += w2[0]*x2[0] + w2[1]*x2[1] + w2[2]*x2[2] + w2[3]*x2[3];
        p1 += w3[0]*x3[0] + w3[1]*x3[1] + w3[2]*x3[2] + w3[3]*x3[3];
        p2 += w4[0]*x4[0] + w4[1]*x4[1] + w4[2]*x4[2] + w4[3]*x4[3];
        p2 += w5[0]*x5[0] + w5[1]*x5[1] + w5[2]*x5[2] + w5[3]*x5[3];
        p3 += w6[0]*x6[0] + w6[1]*x6[1] + w6[2]*x6[2] + w6[3]*x6[3];
        p3 += w7[0]*x7[0] + w7[1]*x7[1] + w7[2]*x7[2] + w7[3]*x7[3];
        // Pin x operands in VGPRs (empty asm, zero instructions): the
        // allocator cannot spill values that must sit in "v" regs here.
        asm volatile("" : "+v"(x0), "+v"(x1), "+v"(x2), "+v"(x3),
                          "+v"(x4), "+v"(x5), "+v"(x6), "+v"(x7));

        float part = (p0 + p1) + (p2 + p3);
#pragma unroll
        for (int off = 32; off >= 1; off >>= 1)
            part += __shfl_xor(part, off, 64);
        const float score = part;                         // wave-uniform
        cur = __builtin_amdgcn_readfirstlane(
                  2 * cur + 1 + (score >= 0.f ? 1 : 0));  // SGPR for next base
        sc[l] = score;
    }
    if (lane == 0) {
        f4* sp = (f4*)(s_all + (size_t)token * DEPTHP1);
        f4 a = {sc[0], sc[1], sc[2],  sc[3]};
        f4 b = {sc[4], sc[5], sc[6],  sc[7]};
        f4 c = {sc[8], sc[9], sc[10], sc[11]};
        sp[0] = a; sp[1] = b; sp[2] = c;
        const int leafid = ((cur - 1) >> 1) - (N_LEAF - 1);
        leaf[token] = leafid;
        atomicAdd(&hist[leafid], 1);
    }
}

// ---------------- K3: exclusive scan over 2048 bins ------------------------
__global__ __launch_bounds__(256) void scan2048(
    const int* __restrict__ hist, int* __restrict__ offsets /*[2049]*/) {
    __shared__ int vals[N_LEAF];
    __shared__ int partial[256];
    const int t = threadIdx.x;
    int sum = 0;
#pragma unroll
    for (int k = 0; k < 8; k++) {
        const int v = hist[t * 8 + k];
        vals[t * 8 + k] = v;
        sum += v;
    }
    partial[t] = sum;
    __syncthreads();
    for (int off = 1; off < 256; off <<= 1) {
        const int v  = partial[t];
        const int vo = (t >= off) ? partial[t - off] : 0;
        __syncthreads();
        partial[t] = v + vo;
        __syncthreads();
    }
    int base = (t > 0) ? partial[t - 1] : 0;
#pragma unroll
    for (int k = 0; k < 8; k++) {
        offsets[t * 8 + k] = base;
        base += vals[t * 8 + k];
    }
    if (t == 255) offsets[N_LEAF] = base;  // == N_TOK
}

// ---------------- K4: scatter; gelu + 16-slot expansion HERE ---------------
__global__ __launch_bounds__(256) void scatter_tokens4(
    const int* __restrict__ leaf, const int* __restrict__ offsets,
    int* __restrict__ cnt, const float* __restrict__ s_all,
    int* __restrict__ order, float* __restrict__ g16 /*[N_TOK][16]*/) {
    const int t = blockIdx.x * 256 + threadIdx.x;
    if (t < N_TOK) {
        const int lf = leaf[t];
        const int pos = offsets[lf] + atomicAdd(&cnt[lf], 1);
        order[pos] = t;
        float g[DEPTHP1];
#pragma unroll
        for (int l = 0; l < DEPTHP1; l++) {
            const float s = s_all[(size_t)t * DEPTHP1 + l];
            g[l] = 0.5f * s * (1.0f + erff(s * 0.70710678118654752f));
        }
        const int b10 = (lf >> 1) & 1;
        const int b11 = lf & 3;
        f4 v0 = {g[0], g[1], g[2], g[3]};
        f4 v1 = {g[4], g[5], g[6], g[7]};
        f4 v2 = {g[8], g[9], b10 ? 0.f : g[10], b10 ? g[10] : 0.f};
        f4 v3 = {b11 == 0 ? g[11] : 0.f, b11 == 1 ? g[11] : 0.f,
                 b11 == 2 ? g[11] : 0.f, b11 == 3 ? g[11] : 0.f};
        f4* gp = (f4*)(g16 + (size_t)pos * 16);
        gp[0] = v0; gp[1] = v1; gp[2] = v2; gp[3] = v3;
    }
}

// ---------------- K5: phase B — register-resident rows, 4-leaf groups ------
__global__ __launch_bounds__(256, 4) void phaseB5(
    const float* __restrict__ w_out_t,  // [N_NODES, D_OUT]
    const float* __restrict__ g16,      // [N_TOK][16] leaf-sorted, expanded
    const int* __restrict__ order,      // [N_TOK]
    const int* __restrict__ offsets,    // [N_LEAF+1]
    float* __restrict__ out) {          // [N_TOK, D_OUT]
    // 1024 blocks = 512 groups x 2 column-halves; XCD swizzle (1024 = 8*128).
    const int bid  = ((blockIdx.x & 7) << 7) | (blockIdx.x >> 3);
    const int grp  = bid >> 1;
    const int half = bid & 1;
    const int lf0  = grp * 4;
    const int start = offsets[lf0];
    const int end   = offsets[lf0 + 4];
    if (start == end) return;
    const int t = threadIdx.x;          // owns f4 col t of this half

    // 16 distinct rows: levels 0-9 shared, 2 @ level 10, 4 @ level 11.
    int node[16];
    const int base1 = lf0 + N_LEAF;     // heap id of leaf lf0 (even, %4==0)
#pragma unroll
    for (int l = 0; l <= 9; l++) node[l] = (base1 >> (11 - l)) - 1;
    node[10] = (base1 >> 1) - 1;
    node[11] = (base1 >> 1);
    node[12] = base1 - 1;
    node[13] = base1;
    node[14] = base1 + 1;
    node[15] = base1 + 2;

    const unsigned voff = (unsigned)t * 16u;
    const size_t cofs = (size_t)half * 1024;
    f4 wA0, wA1, wA2, wA3, wA4, wA5, wA6, wA7;
    f4 wB0, wB1, wB2, wB3, wB4, wB5, wB6, wB7;
#define LDROW(reg, idx) \
    asm volatile("global_load_dwordx4 %0, %1, %2" : "=v"(reg) \
                 : "v"(voff), "s"(w_out_t + (size_t)node[idx] * D_OUT + cofs))
    LDROW(wA0, 0);  LDROW(wA1, 1);  LDROW(wA2, 2);  LDROW(wA3, 3);
    LDROW(wA4, 4);  LDROW(wA5, 5);  LDROW(wA6, 6);  LDROW(wA7, 7);
    LDROW(wB0, 8);  LDROW(wB1, 9);  LDROW(wB2, 10); LDROW(wB3, 11);
    LDROW(wB4, 12); LDROW(wB5, 13); LDROW(wB6, 14); LDROW(wB7, 15);
#undef LDROW
    asm volatile("s_waitcnt vmcnt(0)"
                 : "+v"(wA0), "+v"(wA1), "+v"(wA2), "+v"(wA3),
                   "+v"(wA4), "+v"(wA5), "+v"(wA6), "+v"(wA7) :: "memory");
    asm volatile("" : "+v"(wB0), "+v"(wB1), "+v"(wB2), "+v"(wB3),
                      "+v"(wB4), "+v"(wB5), "+v"(wB6), "+v"(wB7));

    __shared__ float gsl[128];          // 8 tokens x 16 slots
    __shared__ int   ordl[8];

    for (int cs = start; cs < end; cs += 8) {
        __syncthreads();                // prior chunk's readers done
        if (t < 32) {
            const int ti = cs + (t >> 2);
            ((f4*)gsl)[t] = (ti < end)
                ? ((const f4*)(g16 + (size_t)cs * 16))[t] : (f4)0.f;
        } else if (t < 40) {
            const int ti = cs + (t - 32);
            ordl[t - 32] = (ti < end) ? order[ti] : 0;
        }
        __syncthreads();

        const int T = end - cs;         // tokens this chunk: min(T,8)
        f4 acc[8];
#pragma unroll
        for (int tt = 0; tt < 8; tt++) acc[tt] = (f4)0.f;

#pragma unroll
        for (int rb = 0; rb < 4; rb++) {  // slots rb*4..rb*4+3, ascending
#pragma unroll
            for (int tt = 0; tt < 8; tt++) {
                const f4 g4 = ((const f4*)gsl)[tt * 4 + rb];  // broadcast
                if (rb == 0) {
                    acc[tt] += g4[0] * wA0; acc[tt] += g4[1] * wA1;
                    acc[tt] += g4[2] * wA2; acc[tt] += g4[3] * wA3;
                } else if (rb == 1) {
                    acc[tt] += g4[0] * wA4; acc[tt] += g4[1] * wA5;
                    acc[tt] += g4[2] * wA6; acc[tt] += g4[3] * wA7;
                } else if (rb == 2) {
                    acc[tt] += g4[0] * wB0; acc[tt] += g4[1] * wB1;
                    acc[tt] += g4[2] * wB2; acc[tt] += g4[3] * wB3;
                } else {
                    acc[tt] += g4[0] * wB4; acc[tt] += g4[1] * wB5;
                    acc[tt] += g4[2] * wB6; acc[tt] += g4[3] * wB7;
                }
            }
        }
#pragma unroll
        for (int tt = 0; tt < 8; tt++) {
            if (tt < T) {
                ((f4*)(out + (size_t)ordl[tt] * D_OUT + cofs))[t] = acc[tt];
            }
        }
        // Keep the 16 row registers resident across chunk iterations.
        asm volatile("" : "+v"(wA0), "+v"(wA1), "+v"(wA2), "+v"(wA3),
                          "+v"(wA4), "+v"(wA5), "+v"(wA6), "+v"(wA7));
        asm volatile("" : "+v"(wB0), "+v"(wB1), "+v"(wB2), "+v"(wB3),
                          "+v"(wB4), "+v"(wB5), "+v"(wB6), "+v"(wB7));
    }
}

// ---------------- Fallback kernels (small workspace) -----------------------
__global__ __launch_bounds__(256) void transpose_wout64(
    const float* __restrict__ in, float* __restrict__ out) {
    __shared__ float tile[64][65];
    const int n0 = blockIdx.x * 64;
    const int j0 = blockIdx.y * 64;
    const int tx = threadIdx.x;
    const int ty = threadIdx.y;
    const int n = n0 + tx;
#pragma unroll
    for (int k = 0; k < 16; k++) {
        const int r = ty * 16 + k;
        if (n < N_NODES) tile[r][tx] = in[(size_t)(j0 + r) * N_NODES + n];
    }
    __syncthreads();
#pragma unroll
    for (int k = 0; k < 16; k++) {
        const int r = ty * 16 + k;
        const int nn = n0 + r;
        if (nn < N_NODES) out[(size_t)nn * D_OUT + (j0 + tx)] = tile[tx][r];
    }
}

template <bool TRANSPOSED>
__global__ __launch_bounds__(256) void fff_fused(
    const float* __restrict__ x, const float* __restrict__ w_in,
    const float* __restrict__ w_out, float* __restrict__ out) {
    const int wave  = threadIdx.x >> 6;
    const int lane  = threadIdx.x & 63;
    const int token = blockIdx.x * 4 + wave;
    const float4* xrow = (const float4*)(x + (size_t)token * D_IN);
    float xf[32];
#pragma unroll
    for (int c = 0; c < 8; c++) {
        float4 xc = xrow[lane + 64 * c];
        xf[c * 4 + 0] = xc.x; xf[c * 4 + 1] = xc.y;
        xf[c * 4 + 2] = xc.z; xf[c * 4 + 3] = xc.w;
    }
    float acc[32];
#pragma unroll
    for (int k = 0; k < 32; k++) acc[k] = 0.f;
    int cur = 0;
#pragma unroll
    for (int l = 0; l < DEPTHP1; l++) {
        const float4* wrow = (const float4*)(w_in + (size_t)cur * D_IN);
        float part = 0.f;
#pragma unroll
        for (int c = 0; c < 8; c++) {
            float4 wc = wrow[lane + 64 * c];
            part += wc.x * xf[c * 4 + 0]; part += wc.y * xf[c * 4 + 1];
            part += wc.z * xf[c * 4 + 2]; part += wc.w * xf[c * 4 + 3];
        }
#pragma unroll
        for (int off = 32; off >= 1; off >>= 1) part += __shfl_xor(part, off, 64);
        const float score = part;
        const float g = 0.5f * score * (1.0f + erff(score * 0.70710678118654752f));
        if (TRANSPOSED) {
            const float4* orow = (const float4*)(w_out + (size_t)cur * D_OUT);
#pragma unroll
            for (int c = 0; c < 8; c++) {
                float4 oc = orow[lane + 64 * c];
                acc[c * 4 + 0] += g * oc.x; acc[c * 4 + 1] += g * oc.y;
                acc[c * 4 + 2] += g * oc.z; acc[c * 4 + 3] += g * oc.w;
            }
        } else {
#pragma unroll
            for (int c = 0; c < 8; c++)
#pragma unroll
                for (int k = 0; k < 4; k++) {
                    const int j = (lane + 64 * c) * 4 + k;
                    acc[c * 4 + k] += g * w_out[(size_t)j * N_NODES + cur];
                }
        }
        cur = 2 * cur + 1 + (score >= 0.f ? 1 : 0);
    }
    float4* outrow = (float4*)(out + (size_t)token * D_OUT);
#pragma unroll
    for (int c = 0; c < 8; c++) {
        float4 o;
        o.x = acc[c * 4 + 0]; o.y = acc[c * 4 + 1];
        o.z = acc[c * 4 + 2]; o.w = acc[c * 4 + 3];
        outrow[lane + 64 * c] = o;
    }
}

extern "C" void kernel_launch(void* const* d_in, const int* in_sizes, int n_in,
                              void* d_out, int out_size, void* d_ws, size_t ws_size,
                              hipStream_t stream) {
    (void)in_sizes; (void)n_in; (void)out_size;
    const float* x     = (const float*)d_in[0];
    const float* w_in  = (const float*)d_in[1];
    const float* w_out = (const float*)d_in[2];
    float* out = (float*)d_out;

    const size_t wt_bytes   = (size_t)N_NODES * D_OUT * sizeof(float);   // 33.546 MB
    const size_t s_bytes    = (size_t)N_TOK * DEPTHP1 * sizeof(float);   // 393 KB
    const size_t leaf_bytes = (size_t)N_TOK * sizeof(int);
    const size_t ord_bytes  = (size_t)N_TOK * sizeof(int);
    const size_t hist_bytes = (size_t)N_LEAF * sizeof(int);
    const size_t cnt_bytes  = (size_t)N_LEAF * sizeof(int);
    const size_t offs_bytes = (size_t)(N_LEAF + 1) * sizeof(int);
    const size_t g16_bytes  = (size_t)N_TOK * 16 * sizeof(float);        // 512 KB
    const size_t need = wt_bytes + s_bytes + leaf_bytes + ord_bytes +
                        hist_bytes + cnt_bytes + offs_bytes + g16_bytes + 64;

    if (ws_size >= need) {
        char* p = (char*)d_ws;
        float* w_out_t = (float*)p;  p += wt_bytes;
        float* s_all   = (float*)p;  p += s_bytes;
        int*   leaf    = (int*)p;    p += leaf_bytes;
        int*   order   = (int*)p;    p += ord_bytes;
        int*   hist    = (int*)p;    p += hist_bytes;   // hist+cnt contiguous
        int*   cnt     = (int*)p;    p += cnt_bytes;
        int*   offsets = (int*)p;    p += offs_bytes;
        float* g16     = (float*)p;

        transpose_wout64z<<<dim3(64, 32), dim3(64, 4), 0, stream>>>(
            w_out, w_out_t, hist);
        phaseA4<<<N_TOK / 4, 256, 0, stream>>>(x, w_in, s_all, leaf, hist);
        scan2048<<<1, 256, 0, stream>>>(hist, offsets);
        scatter_tokens4<<<N_TOK / 256, 256, 0, stream>>>(leaf, offsets, cnt,
                                                         s_all, order, g16);
        phaseB5<<<1024, 256, 0, stream>>>(w_out_t, g16, order, offsets, out);
    } else if (ws_size >= wt_bytes) {
        float* w_out_t = (float*)d_ws;
        transpose_wout64<<<dim3((N_NODES + 63) / 64, D_OUT / 64), dim3(64, 4),
                           0, stream>>>(w_out, w_out_t);
        fff_fused<true><<<N_TOK / 4, 256, 0, stream>>>(x, w_in, w_out_t, out);
    } else {
        fff_fused<false><<<N_TOK / 4, 256, 0, stream>>>(x, w_in, w_out, out);
    }
}